// Round 3
// baseline (1411.393 us; speedup 1.0000x reference)
//
#include <hip/hip_runtime.h>
#include <hip/hip_bf16.h>
#include <cstdint>

// ---------------------------------------------------------------------------
// KAN 2-layer forward as two bf16 MFMA GEMMs. OUTPUT IS FP32 (reference is
// pure-fp32 JAX; round-1/2 failure was writing bf16 into the float* d_out).
//   Aug[b, c*I+i] = basis_c(x[b,i]) for c<8, silu(x[b,i]) for c==8   (bf16)
//   W[o, c*I+i]   = coef[o,i,c]*sp[o,i]*mask[o,i] (c<8), sb*mask (c==8) (bf16)
//   layer(b,o)    = sum_k Aug[b,k]*W[o,k] + bias[o]   (fp32 accum, fp32 out)
// ws layout: h1 fp32 [0,64MiB) | W bf16 [64,100MiB) | Aug bf16 [100,244MiB)
// (r1 ran this exact footprint without fault -> ws_size >= 244 MiB.)
// ---------------------------------------------------------------------------

typedef __attribute__((ext_vector_type(8))) short short8;
typedef __attribute__((ext_vector_type(4))) float f32x4;

#define GLD16(gp, lp)                                                          \
  __builtin_amdgcn_global_load_lds(                                           \
      (const __attribute__((address_space(1))) unsigned int*)(gp),             \
      (__attribute__((address_space(3))) unsigned int*)(lp), 16, 0, 0)

// ---- pack weights: W[o, c*I+i], bf16 --------------------------------------
__global__ void prep_w(const float* __restrict__ coef, const float* __restrict__ sb,
                       const float* __restrict__ sp, const float* __restrict__ mask,
                       __hip_bfloat16* __restrict__ W, int O, int I) {
  long idx = (long)blockIdx.x * blockDim.x + threadIdx.x;
  long total = (long)O * I;
  if (idx >= total) return;
  int i = (int)(idx % I);
  int o = (int)(idx / I);
  float mk  = mask[idx];
  float spm = sp[idx] * mk;
  float sbm = sb[idx] * mk;
  const float4* cf = (const float4*)(coef + (size_t)idx * 8);
  float4 c0 = cf[0], c1 = cf[1];
  __hip_bfloat16* base = W + (size_t)o * (size_t)(9 * I) + i;
  base[(size_t)0 * I] = __float2bfloat16(c0.x * spm);
  base[(size_t)1 * I] = __float2bfloat16(c0.y * spm);
  base[(size_t)2 * I] = __float2bfloat16(c0.z * spm);
  base[(size_t)3 * I] = __float2bfloat16(c0.w * spm);
  base[(size_t)4 * I] = __float2bfloat16(c1.x * spm);
  base[(size_t)5 * I] = __float2bfloat16(c1.y * spm);
  base[(size_t)6 * I] = __float2bfloat16(c1.z * spm);
  base[(size_t)7 * I] = __float2bfloat16(c1.w * spm);
  base[(size_t)8 * I] = __float2bfloat16(sbm);
}

// ---- expand activations: Aug[b, c*I+i], i-pairs, packed bf16x2 stores -----
// Uniform knots: grid[m] = (m-3)*0.4 - 1.0, m=0..11. u=(x+2.2)/0.4, j=floor(u).
// Nonzero basis c = j-3..j with cardinal cubic weights; B_c = w_{3-(j-c)}.
// Out-of-domain x (j<0 or j>10) -> all spline channels 0 (matches reference).
__device__ __forceinline__ void basis8(float x, float* w, int& j) {
  float u  = (x + 2.2f) * 2.5f;
  float fj = floorf(u);
  j = (int)fj;
  float t  = u - fj;
  float omt = 1.0f - t;
  float t2 = t * t, t3 = t2 * t;
  w[0] = omt * omt * omt * (1.0f / 6.0f);                    // d==3
  w[1] = (3.0f * t3 - 6.0f * t2 + 4.0f) * (1.0f / 6.0f);     // d==2
  w[2] = (-3.0f * t3 + 3.0f * t2 + 3.0f * t + 1.0f) * (1.0f / 6.0f); // d==1
  w[3] = t3 * (1.0f / 6.0f);                                 // d==0
}

__global__ void expand_aug(const float* __restrict__ src,
                           __hip_bfloat16* __restrict__ aug,
                           long totalPairs, int I) {
  long idx = (long)blockIdx.x * blockDim.x + threadIdx.x;
  if (idx >= totalPairs) return;
  int  half = I >> 1;
  int  ip = (int)(idx % half);
  long b  = idx / half;
  int  i  = ip << 1;
  float2 xv = *(const float2*)(src + b * (size_t)I + i);
  float s0 = xv.x / (1.0f + __expf(-xv.x));
  float s1 = xv.y / (1.0f + __expf(-xv.y));
  float wa[4], wb[4];
  int j0, j1;
  basis8(xv.x, wa, j0);
  basis8(xv.y, wb, j1);

  __hip_bfloat16* base = aug + b * (size_t)(9 * I) + i;
#pragma unroll
  for (int c = 0; c < 8; c++) {
    int d0 = j0 - c, d1 = j1 - c;
    float v0 = 0.0f, v1 = 0.0f;
    v0 = (d0 == 0) ? wa[3] : v0;
    v0 = (d0 == 1) ? wa[2] : v0;
    v0 = (d0 == 2) ? wa[1] : v0;
    v0 = (d0 == 3) ? wa[0] : v0;
    v1 = (d1 == 0) ? wb[3] : v1;
    v1 = (d1 == 1) ? wb[2] : v1;
    v1 = (d1 == 2) ? wb[1] : v1;
    v1 = (d1 == 3) ? wb[0] : v1;
    __hip_bfloat162 p;
    p.x = __float2bfloat16(v0);
    p.y = __float2bfloat16(v1);
    *(__hip_bfloat162*)(base + (size_t)c * I) = p;
  }
  __hip_bfloat162 ps;
  ps.x = __float2bfloat16(s0);
  ps.y = __float2bfloat16(s1);
  *(__hip_bfloat162*)(base + (size_t)8 * I) = ps;
}

// ---- MFMA GEMM: C[m,n] = sum_k A[m,k]*Bw[n,k] + bias[n], fp32 out ---------
// m97-style: 128x128 tile, 4 waves (2x2), BK=32, global_load_lds(16B) staging.
// mfma_f32_16x16x32_bf16 layouts (HW-verified, learn_hip m89/m91):
//   A: lane l elem e -> A[l&15][8*(l>>4)+e]
//   B: lane l elem e -> B[8*(l>>4)+e][l&15]
//   D: lane l reg  r -> D[4*(l>>4)+r][l&15]
__global__ __launch_bounds__(256) void gemm_kan(
    const __hip_bfloat16* __restrict__ A, const __hip_bfloat16* __restrict__ Bw,
    const float* __restrict__ bias, float* __restrict__ Cout, int N, int K) {
  __shared__ __attribute__((aligned(16))) unsigned short smA[128 * 32];
  __shared__ __attribute__((aligned(16))) unsigned short smB[128 * 32];
  int t = threadIdx.x;
  int w = t >> 6, l = t & 63;
  int wr = w >> 1, wc = w & 1;
  int lr = l & 15, kh = (l >> 4) << 3;
  size_t brow = (size_t)blockIdx.y * 128, bcol = (size_t)blockIdx.x * 128;

  f32x4 acc[4][4];
#pragma unroll
  for (int m = 0; m < 4; m++)
#pragma unroll
    for (int n = 0; n < 4; n++) acc[m][n] = (f32x4){0.f, 0.f, 0.f, 0.f};

  int srow = t >> 2;            // staging row 0..63 (+64 for 2nd issue)
  int scol = (t & 3) << 3;      // staging col (bf16 elems)
  const __hip_bfloat16* gA = A + (brow + srow) * (size_t)K + scol;
  const __hip_bfloat16* gB = Bw + (bcol + srow) * (size_t)K + scol;
  char* lA = (char*)smA + w * 1024;  // wave-uniform LDS base; lane i -> +16*i
  char* lB = (char*)smB + w * 1024;
  size_t rowK64 = (size_t)64 * K;

  for (int k0 = 0; k0 < K; k0 += 32) {
    __syncthreads();
    GLD16(gA + k0, lA);
    GLD16(gA + rowK64 + k0, lA + 4096);
    GLD16(gB + k0, lB);
    GLD16(gB + rowK64 + k0, lB + 4096);
    __syncthreads();  // compiler drains vmcnt before s_barrier

    short8 af[4], bq[4];
    const unsigned short* pa = smA + (wr * 64 + lr) * 32 + kh;
    const unsigned short* pb = smB + (wc * 64 + lr) * 32 + kh;
#pragma unroll
    for (int m = 0; m < 4; m++) af[m] = *(const short8*)(pa + m * 512);
#pragma unroll
    for (int n = 0; n < 4; n++) bq[n] = *(const short8*)(pb + n * 512);
#pragma unroll
    for (int m = 0; m < 4; m++)
#pragma unroll
      for (int n = 0; n < 4; n++)
        acc[m][n] = __builtin_amdgcn_mfma_f32_16x16x32_bf16(af[m], bq[n], acc[m][n], 0, 0, 0);
  }

  int orow = (l >> 4) << 2;
#pragma unroll
  for (int n = 0; n < 4; n++) {
    size_t col = bcol + (size_t)wc * 64 + n * 16 + lr;
    float bv = bias[col];
#pragma unroll
    for (int m = 0; m < 4; m++) {
      size_t row = brow + (size_t)wr * 64 + m * 16 + orow;
#pragma unroll
      for (int r = 0; r < 4; r++)
        Cout[(row + r) * (size_t)N + col] = acc[m][n][r] + bv;
    }
  }
}

// ---------------------------------------------------------------------------
extern "C" void kernel_launch(void* const* d_in, const int* in_sizes, int n_in,
                              void* d_out, int out_size, void* d_ws, size_t ws_size,
                              hipStream_t stream) {
  const float* x     = (const float*)d_in[0];
  const float* coef0 = (const float*)d_in[1];
  const float* sb0   = (const float*)d_in[2];
  const float* sp0   = (const float*)d_in[3];
  const float* mask0 = (const float*)d_in[4];
  const float* bias0 = (const float*)d_in[5];
  const float* coef1 = (const float*)d_in[6];
  const float* sb1   = (const float*)d_in[7];
  const float* sp1   = (const float*)d_in[8];
  const float* mask1 = (const float*)d_in[9];
  const float* bias1 = (const float*)d_in[10];
  float* out = (float*)d_out;   // reference output dtype is float32

  const int B = 8192, D0 = 1024, D1 = 2048, D2 = 1024;
  const int K0 = 9 * D0;   // 9216
  const int K1 = 9 * D1;   // 18432

  char* ws = (char*)d_ws;
  float*          h1  = (float*)ws;                                   // 64 MiB
  __hip_bfloat16* W   = (__hip_bfloat16*)(ws + (size_t)67108864);     // 36 MiB
  __hip_bfloat16* Aug = (__hip_bfloat16*)(ws + (size_t)104857600);    // 144 MiB

  // ---- layer 0: full batch ----
  {
    long nw = (long)D1 * D0;
    prep_w<<<(unsigned)((nw + 255) / 256), 256, 0, stream>>>(coef0, sb0, sp0, mask0, W, D1, D0);
    long np = (long)B * (D0 / 2);
    expand_aug<<<(unsigned)((np + 255) / 256), 256, 0, stream>>>(x, Aug, np, D0);
    dim3 g0(D1 / 128, B / 128);  // (16, 64)
    gemm_kan<<<g0, 256, 0, stream>>>(Aug, W, bias0, h1, D1, K0);
  }

  // ---- layer 1: 2 batch chunks of 4096 (Aug region reuse) ----
  {
    long nw = (long)D2 * D1;
    prep_w<<<(unsigned)((nw + 255) / 256), 256, 0, stream>>>(coef1, sb1, sp1, mask1, W, D2, D1);
    const int CH = 4096;
    for (int ch = 0; ch < 2; ch++) {
      long np = (long)CH * (D1 / 2);
      expand_aug<<<(unsigned)((np + 255) / 256), 256, 0, stream>>>(
          h1 + (size_t)ch * CH * D1, Aug, np, D1);
      dim3 g1(D2 / 128, CH / 128);  // (8, 32)
      gemm_kan<<<g1, 256, 0, stream>>>(Aug, W, bias1,
                                       out + (size_t)ch * CH * D2, D2, K1);
    }
  }
}

// Round 4
// 1405.681 us; speedup vs baseline: 1.0041x; 1.0041x over previous
//
#include <hip/hip_runtime.h>
#include <hip/hip_bf16.h>
#include <cstdint>

// ---------------------------------------------------------------------------
// KAN 2-layer forward as two bf16 MFMA GEMMs (fp32 output).
//   Aug[b, c*I+i] = basis_c(x[b,i]) for c<8, silu(x[b,i]) for c==8   (bf16)
//   W[o, c*I+i]   = coef[o,i,c]*sp[o,i]*mask[o,i] (c<8), sb*mask (c==8) (bf16)
//   layer(b,o)    = sum_k Aug[b,k]*W[o,k] + bias[o]   (fp32 accum/out)
//
// Round-4 changes (vs r3 pass @1411us):
//  * Layer-1 un-chunked when ws_size allows (full-batch Aug = 302MB): r3
//    counters showed gemm1 chunks at Occupancy 9.9%/MfmaUtil 12% (256 blocks
//    = 1/CU, no latency hiding) vs gemm0's 22%/26%. Full batch -> 512 blocks.
//    Runtime-gated on ws_size; fallback = r3's proven CH=4096 path.
//  * XCD-aware bijective block swizzle in gemm (all grids %8==0): groups
//    same-A-panel tiles on one XCD's L2 (FETCH 707MB -> ~450MB expected).
// ws layout: h1 fp32 [0,64MiB) | W bf16 [64,100MiB) | Aug bf16 [100MiB, ...)
// ---------------------------------------------------------------------------

typedef __attribute__((ext_vector_type(8))) short short8;
typedef __attribute__((ext_vector_type(4))) float f32x4;

#define GLD16(gp, lp)                                                          \
  __builtin_amdgcn_global_load_lds(                                           \
      (const __attribute__((address_space(1))) unsigned int*)(gp),             \
      (__attribute__((address_space(3))) unsigned int*)(lp), 16, 0, 0)

// ---- pack weights: W[o, c*I+i], bf16 --------------------------------------
__global__ void prep_w(const float* __restrict__ coef, const float* __restrict__ sb,
                       const float* __restrict__ sp, const float* __restrict__ mask,
                       __hip_bfloat16* __restrict__ W, int O, int I) {
  long idx = (long)blockIdx.x * blockDim.x + threadIdx.x;
  long total = (long)O * I;
  if (idx >= total) return;
  int i = (int)(idx % I);
  int o = (int)(idx / I);
  float mk  = mask[idx];
  float spm = sp[idx] * mk;
  float sbm = sb[idx] * mk;
  const float4* cf = (const float4*)(coef + (size_t)idx * 8);
  float4 c0 = cf[0], c1 = cf[1];
  __hip_bfloat16* base = W + (size_t)o * (size_t)(9 * I) + i;
  base[(size_t)0 * I] = __float2bfloat16(c0.x * spm);
  base[(size_t)1 * I] = __float2bfloat16(c0.y * spm);
  base[(size_t)2 * I] = __float2bfloat16(c0.z * spm);
  base[(size_t)3 * I] = __float2bfloat16(c0.w * spm);
  base[(size_t)4 * I] = __float2bfloat16(c1.x * spm);
  base[(size_t)5 * I] = __float2bfloat16(c1.y * spm);
  base[(size_t)6 * I] = __float2bfloat16(c1.z * spm);
  base[(size_t)7 * I] = __float2bfloat16(c1.w * spm);
  base[(size_t)8 * I] = __float2bfloat16(sbm);
}

// ---- expand activations: Aug[b, c*I+i], i-pairs, packed bf16x2 stores -----
// Uniform knots grid[m]=(m-3)*0.4-1.0: u=(x+2.2)*2.5, j=floor(u); nonzero
// basis c=j-3..j with cardinal cubic weights; B_c=0 otherwise (also covers
// out-of-domain x, matching the reference).
__device__ __forceinline__ void basis8(float x, float* w, int& j) {
  float u  = (x + 2.2f) * 2.5f;
  float fj = floorf(u);
  j = (int)fj;
  float t  = u - fj;
  float omt = 1.0f - t;
  float t2 = t * t, t3 = t2 * t;
  w[0] = omt * omt * omt * (1.0f / 6.0f);                              // d==3
  w[1] = (3.0f * t3 - 6.0f * t2 + 4.0f) * (1.0f / 6.0f);               // d==2
  w[2] = (-3.0f * t3 + 3.0f * t2 + 3.0f * t + 1.0f) * (1.0f / 6.0f);   // d==1
  w[3] = t3 * (1.0f / 6.0f);                                           // d==0
}

__global__ void expand_aug(const float* __restrict__ src,
                           __hip_bfloat16* __restrict__ aug,
                           long totalPairs, int I) {
  long idx = (long)blockIdx.x * blockDim.x + threadIdx.x;
  if (idx >= totalPairs) return;
  int  half = I >> 1;
  int  ip = (int)(idx % half);
  long b  = idx / half;
  int  i  = ip << 1;
  float2 xv = *(const float2*)(src + b * (size_t)I + i);
  float s0 = xv.x / (1.0f + __expf(-xv.x));
  float s1 = xv.y / (1.0f + __expf(-xv.y));
  float wa[4], wb[4];
  int j0, j1;
  basis8(xv.x, wa, j0);
  basis8(xv.y, wb, j1);

  __hip_bfloat16* base = aug + b * (size_t)(9 * I) + i;
#pragma unroll
  for (int c = 0; c < 8; c++) {
    int d0 = j0 - c, d1 = j1 - c;
    float v0 = 0.0f, v1 = 0.0f;
    v0 = (d0 == 0) ? wa[3] : v0;
    v0 = (d0 == 1) ? wa[2] : v0;
    v0 = (d0 == 2) ? wa[1] : v0;
    v0 = (d0 == 3) ? wa[0] : v0;
    v1 = (d1 == 0) ? wb[3] : v1;
    v1 = (d1 == 1) ? wb[2] : v1;
    v1 = (d1 == 2) ? wb[1] : v1;
    v1 = (d1 == 3) ? wb[0] : v1;
    __hip_bfloat162 p;
    p.x = __float2bfloat16(v0);
    p.y = __float2bfloat16(v1);
    *(__hip_bfloat162*)(base + (size_t)c * I) = p;
  }
  __hip_bfloat162 ps;
  ps.x = __float2bfloat16(s0);
  ps.y = __float2bfloat16(s1);
  *(__hip_bfloat162*)(base + (size_t)8 * I) = ps;
}

// ---- MFMA GEMM: C[m,n] = sum_k A[m,k]*Bw[n,k] + bias[n], fp32 out ---------
// m97-style: 128x128 tile, 4 waves (2x2), BK=32, global_load_lds(16B),
// XCD-aware bijective block swizzle (requires gridDim.x*gridDim.y % 8 == 0).
// mfma_f32_16x16x32_bf16 layouts (HW-verified, learn_hip m89/m91):
//   A: lane l elem e -> A[l&15][8*(l>>4)+e]
//   B: lane l elem e -> B[8*(l>>4)+e][l&15]
//   D: lane l reg  r -> D[4*(l>>4)+r][l&15]
__global__ __launch_bounds__(256) void gemm_kan(
    const __hip_bfloat16* __restrict__ A, const __hip_bfloat16* __restrict__ Bw,
    const float* __restrict__ bias, float* __restrict__ Cout, int N, int K) {
  __shared__ __attribute__((aligned(16))) unsigned short smA[128 * 32];
  __shared__ __attribute__((aligned(16))) unsigned short smB[128 * 32];
  int t = threadIdx.x;
  int w = t >> 6, l = t & 63;
  int wr = w >> 1, wc = w & 1;
  int lr = l & 15, kh = (l >> 4) << 3;

  // XCD swizzle: HW dispatches linear ids round-robin over 8 XCDs; remap so
  // each XCD computes a contiguous range of row-major tile ids (A-panel reuse
  // stays in one XCD's L2). Bijective since nwg % 8 == 0.
  unsigned nwg = gridDim.x * gridDim.y;
  unsigned lin = blockIdx.y * gridDim.x + blockIdx.x;
  unsigned swz = (lin & 7) * (nwg >> 3) + (lin >> 3);
  unsigned bx = swz % gridDim.x, by = swz / gridDim.x;
  size_t brow = (size_t)by * 128, bcol = (size_t)bx * 128;

  f32x4 acc[4][4];
#pragma unroll
  for (int m = 0; m < 4; m++)
#pragma unroll
    for (int n = 0; n < 4; n++) acc[m][n] = (f32x4){0.f, 0.f, 0.f, 0.f};

  int srow = t >> 2;            // staging row 0..63 (+64 for 2nd issue)
  int scol = (t & 3) << 3;      // staging col (bf16 elems)
  const __hip_bfloat16* gA = A + (brow + srow) * (size_t)K + scol;
  const __hip_bfloat16* gB = Bw + (bcol + srow) * (size_t)K + scol;
  char* lA = (char*)smA + w * 1024;  // wave-uniform LDS base; lane i -> +16*i
  char* lB = (char*)smB + w * 1024;
  size_t rowK64 = (size_t)64 * K;

  for (int k0 = 0; k0 < K; k0 += 32) {
    __syncthreads();
    GLD16(gA + k0, lA);
    GLD16(gA + rowK64 + k0, lA + 4096);
    GLD16(gB + k0, lB);
    GLD16(gB + rowK64 + k0, lB + 4096);
    __syncthreads();  // compiler drains vmcnt before s_barrier

    short8 af[4], bq[4];
    const unsigned short* pa = smA + (wr * 64 + lr) * 32 + kh;
    const unsigned short* pb = smB + (wc * 64 + lr) * 32 + kh;
#pragma unroll
    for (int m = 0; m < 4; m++) af[m] = *(const short8*)(pa + m * 512);
#pragma unroll
    for (int n = 0; n < 4; n++) bq[n] = *(const short8*)(pb + n * 512);
#pragma unroll
    for (int m = 0; m < 4; m++)
#pragma unroll
      for (int n = 0; n < 4; n++)
        acc[m][n] = __builtin_amdgcn_mfma_f32_16x16x32_bf16(af[m], bq[n], acc[m][n], 0, 0, 0);
  }

  int orow = (l >> 4) << 2;
#pragma unroll
  for (int n = 0; n < 4; n++) {
    size_t col = bcol + (size_t)wc * 64 + n * 16 + lr;
    float bv = bias[col];
#pragma unroll
    for (int m = 0; m < 4; m++) {
      size_t row = brow + (size_t)wr * 64 + m * 16 + orow;
#pragma unroll
      for (int r = 0; r < 4; r++)
        Cout[(row + r) * (size_t)N + col] = acc[m][n][r] + bv;
    }
  }
}

// ---------------------------------------------------------------------------
extern "C" void kernel_launch(void* const* d_in, const int* in_sizes, int n_in,
                              void* d_out, int out_size, void* d_ws, size_t ws_size,
                              hipStream_t stream) {
  const float* x     = (const float*)d_in[0];
  const float* coef0 = (const float*)d_in[1];
  const float* sb0   = (const float*)d_in[2];
  const float* sp0   = (const float*)d_in[3];
  const float* mask0 = (const float*)d_in[4];
  const float* bias0 = (const float*)d_in[5];
  const float* coef1 = (const float*)d_in[6];
  const float* sb1   = (const float*)d_in[7];
  const float* sp1   = (const float*)d_in[8];
  const float* mask1 = (const float*)d_in[9];
  const float* bias1 = (const float*)d_in[10];
  float* out = (float*)d_out;   // reference output dtype is float32

  const int B = 8192, D0 = 1024, D1 = 2048, D2 = 1024;
  const int K0 = 9 * D0;   // 9216
  const int K1 = 9 * D1;   // 18432

  char* ws = (char*)d_ws;
  float*          h1  = (float*)ws;                                   // 64 MiB
  __hip_bfloat16* W   = (__hip_bfloat16*)(ws + (size_t)67108864);     // 36 MiB
  __hip_bfloat16* Aug = (__hip_bfloat16*)(ws + (size_t)104857600);

  // full-batch L1 needs 100MiB + 8192*18432*2 = 406,847,488 bytes of ws
  const bool fullL1 = ws_size >= (size_t)104857600 + (size_t)B * K1 * 2;

  // ---- layer 0: full batch (Aug = 144MiB, proven fit) ----
  {
    long nw = (long)D1 * D0;
    prep_w<<<(unsigned)((nw + 255) / 256), 256, 0, stream>>>(coef0, sb0, sp0, mask0, W, D1, D0);
    long np = (long)B * (D0 / 2);
    expand_aug<<<(unsigned)((np + 255) / 256), 256, 0, stream>>>(x, Aug, np, D0);
    dim3 g0(D1 / 128, B / 128);  // (16, 64) = 1024 blocks
    gemm_kan<<<g0, 256, 0, stream>>>(Aug, W, bias0, h1, D1, K0);
  }

  // ---- layer 1 ----
  {
    long nw = (long)D2 * D1;
    prep_w<<<(unsigned)((nw + 255) / 256), 256, 0, stream>>>(coef1, sb1, sp1, mask1, W, D2, D1);
    const int CH = fullL1 ? B : 4096;
    for (int ch = 0; ch < B / CH; ch++) {
      long np = (long)CH * (D1 / 2);
      expand_aug<<<(unsigned)((np + 255) / 256), 256, 0, stream>>>(
          h1 + (size_t)ch * CH * D1, Aug, np, D1);
      dim3 g1(D2 / 128, CH / 128);  // full: (8,64)=512 blocks; fb: (8,32)=256
      gemm_kan<<<g1, 256, 0, stream>>>(Aug, W, bias1,
                                       out + (size_t)ch * CH * D2, D2, K1);
    }
  }
}

// Round 5
// 1126.906 us; speedup vs baseline: 1.2524x; 1.2474x over previous
//
#include <hip/hip_runtime.h>
#include <hip/hip_bf16.h>
#include <cstdint>

// ---------------------------------------------------------------------------
// KAN 2-layer forward as two bf16 MFMA GEMMs (fp32 output).
// Round-5: 8-phase-style deep-pipelined GEMM (T2+T3+T4+T5):
//   256xBN tile, BK=32, 8 waves (2M x 4N), 512 threads, 64KB LDS dbuf.
//   Per K-tile: stage(kt+1) -> counted vmcnt(4) [never 0 in loop] -> barrier
//   -> {reads+16 MFMA}x2 phases with setprio, barriers between.
//   LDS XOR-swizzle ((row&3)<<4) with pre-swizzled GLOBAL source (linear
//   global_load_lds dest) + swizzled ds_read addr (rule 21: both-sides).
//   gemm1 uses BN=128 so grid = 8x32 = 256 blocks (full GPU, no split-K).
// ws layout: h1 fp32 [0,64MiB) | W bf16 [64,100MiB) | Aug bf16 [100MiB,...)
// ---------------------------------------------------------------------------

typedef __attribute__((ext_vector_type(8))) short short8;
typedef __attribute__((ext_vector_type(4))) float f32x4;

#define GLD16(gp, lp)                                                          \
  __builtin_amdgcn_global_load_lds(                                           \
      (const __attribute__((address_space(1))) unsigned int*)(gp),             \
      (__attribute__((address_space(3))) unsigned int*)(lp), 16, 0, 0)

// ---- pack weights: W[o, c*I+i], bf16 --------------------------------------
__global__ void prep_w(const float* __restrict__ coef, const float* __restrict__ sb,
                       const float* __restrict__ sp, const float* __restrict__ mask,
                       __hip_bfloat16* __restrict__ W, int O, int I) {
  long idx = (long)blockIdx.x * blockDim.x + threadIdx.x;
  long total = (long)O * I;
  if (idx >= total) return;
  int i = (int)(idx % I);
  int o = (int)(idx / I);
  float mk  = mask[idx];
  float spm = sp[idx] * mk;
  float sbm = sb[idx] * mk;
  const float4* cf = (const float4*)(coef + (size_t)idx * 8);
  float4 c0 = cf[0], c1 = cf[1];
  __hip_bfloat16* base = W + (size_t)o * (size_t)(9 * I) + i;
  base[(size_t)0 * I] = __float2bfloat16(c0.x * spm);
  base[(size_t)1 * I] = __float2bfloat16(c0.y * spm);
  base[(size_t)2 * I] = __float2bfloat16(c0.z * spm);
  base[(size_t)3 * I] = __float2bfloat16(c0.w * spm);
  base[(size_t)4 * I] = __float2bfloat16(c1.x * spm);
  base[(size_t)5 * I] = __float2bfloat16(c1.y * spm);
  base[(size_t)6 * I] = __float2bfloat16(c1.z * spm);
  base[(size_t)7 * I] = __float2bfloat16(c1.w * spm);
  base[(size_t)8 * I] = __float2bfloat16(sbm);
}

// ---- expand activations: Aug[b, c*I+i], i-pairs, packed bf16x2 stores -----
__device__ __forceinline__ void basis8(float x, float* w, int& j) {
  float u  = (x + 2.2f) * 2.5f;
  float fj = floorf(u);
  j = (int)fj;
  float t  = u - fj;
  float omt = 1.0f - t;
  float t2 = t * t, t3 = t2 * t;
  w[0] = omt * omt * omt * (1.0f / 6.0f);                              // d==3
  w[1] = (3.0f * t3 - 6.0f * t2 + 4.0f) * (1.0f / 6.0f);               // d==2
  w[2] = (-3.0f * t3 + 3.0f * t2 + 3.0f * t + 1.0f) * (1.0f / 6.0f);   // d==1
  w[3] = t3 * (1.0f / 6.0f);                                           // d==0
}

__global__ void expand_aug(const float* __restrict__ src,
                           __hip_bfloat16* __restrict__ aug,
                           long totalPairs, int I) {
  long idx = (long)blockIdx.x * blockDim.x + threadIdx.x;
  if (idx >= totalPairs) return;
  int  half = I >> 1;
  int  ip = (int)(idx % half);
  long b  = idx / half;
  int  i  = ip << 1;
  float2 xv = *(const float2*)(src + b * (size_t)I + i);
  float s0 = xv.x / (1.0f + __expf(-xv.x));
  float s1 = xv.y / (1.0f + __expf(-xv.y));
  float wa[4], wb[4];
  int j0, j1;
  basis8(xv.x, wa, j0);
  basis8(xv.y, wb, j1);

  __hip_bfloat16* base = aug + b * (size_t)(9 * I) + i;
#pragma unroll
  for (int c = 0; c < 8; c++) {
    int d0 = j0 - c, d1 = j1 - c;
    float v0 = 0.0f, v1 = 0.0f;
    v0 = (d0 == 0) ? wa[3] : v0;
    v0 = (d0 == 1) ? wa[2] : v0;
    v0 = (d0 == 2) ? wa[1] : v0;
    v0 = (d0 == 3) ? wa[0] : v0;
    v1 = (d1 == 0) ? wb[3] : v1;
    v1 = (d1 == 1) ? wb[2] : v1;
    v1 = (d1 == 2) ? wb[1] : v1;
    v1 = (d1 == 3) ? wb[0] : v1;
    __hip_bfloat162 p;
    p.x = __float2bfloat16(v0);
    p.y = __float2bfloat16(v1);
    *(__hip_bfloat162*)(base + (size_t)c * I) = p;
  }
  __hip_bfloat162 ps;
  ps.x = __float2bfloat16(s0);
  ps.y = __float2bfloat16(s1);
  *(__hip_bfloat162*)(base + (size_t)8 * I) = ps;
}

// ---- 8-phase GEMM: C[m,n] = sum_k A[m,k]*Bw[n,k] + bias[n], fp32 out ------
// BM=256 x BN (256 or 128), BK=32, 8 waves = 2M x 4N, per-wave out 128 x BN/4.
// LDS per buf: A 256x32 bf16 (16KB), B BNx32 bf16. Rows are 64B; element
// (row, kbyte) stored at kbyte ^ ((row&3)<<4)  [balanced: 8 lanes/bank-quad].
// global_load_lds writes linearly -> global SOURCE is pre-swizzled.
// Schedule per K-tile kt (buf b=kt&1): stage A,B(kt+1)->buf b^1 (issued a
// full K-tile before their wait) ; vmcnt(keep=loads-per-tile) ; barrier ;
// ph0: read bfrag[all]+afrag[0..3], 16(8) MFMA ; barrier ;
// ph1: read afrag[4..7], 16(8) MFMA ; barrier.
// WAR chain: every ds_read is consumed by MFMA (compiler lgkmcnt) before the
// barrier that releases the next overwriting stage.
template <int BN>
__global__ __launch_bounds__(512, 2) void gemm8p(
    const __hip_bfloat16* __restrict__ A, const __hip_bfloat16* __restrict__ Bw,
    const float* __restrict__ bias, float* __restrict__ Cout, int N, int K) {
  constexpr int WN   = BN / 4;    // per-wave cols
  constexpr int NREP = BN / 64;   // 16-col frags per wave
  constexpr int BNB  = BN * 64;   // bytes per B buffer
  __shared__ __attribute__((aligned(16))) char lds[32768 + 2 * BNB];

  const int t = threadIdx.x;
  const int w = t >> 6, l = t & 63;
  const int wr = w >> 2, wc = w & 3;
  const int lr = l & 15;
  const int kbs = ((l >> 4) * 16) ^ ((lr & 3) << 4);  // swizzled k-byte

  // XCD-aware bijective swizzle (grid %8 == 0)
  unsigned nwg = gridDim.x * gridDim.y;
  unsigned lin = blockIdx.y * gridDim.x + blockIdx.x;
  unsigned swz = (lin & 7) * (nwg >> 3) + (lin >> 3);
  unsigned bx = swz % gridDim.x, by = swz / gridDim.x;
  size_t brow = (size_t)by * 256, bcol = (size_t)bx * BN;

  f32x4 acc[8][NREP];
#pragma unroll
  for (int m = 0; m < 8; m++)
#pragma unroll
    for (int n = 0; n < NREP; n++) acc[m][n] = (f32x4){0.f, 0.f, 0.f, 0.f};

  // staging: thread t covers LDS-linear offset t*16 of each 8KB chunk.
  // LDS offset o holds global (row=o/64, kbyte=(o%64)^((row&3)<<4)).
  const int srow  = t >> 2;                                  // 0..127
  const int scolb = ((t & 3) * 16) ^ ((srow & 3) << 4);      // byte col
  const __hip_bfloat16* gA0 = A + (brow + srow) * (size_t)K + (scolb >> 1);
  const __hip_bfloat16* gA1 = gA0 + (size_t)128 * K;
  const __hip_bfloat16* gB0 = Bw + (bcol + srow) * (size_t)K + (scolb >> 1);
  const __hip_bfloat16* gB1 = gB0 + (size_t)128 * K;         // BN=256 only

  char* ldsp = (char*)lds;
  const int paOff = (wr * 128 + lr) * 64 + kbs;              // + m*1024 + b*16384
  const int pbOff = 32768 + (wc * WN + lr) * 64 + kbs;       // + n*1024 + b*BNB

  // prologue: stage K-tile 0 into buf 0
  GLD16(gA0, ldsp + w * 1024);
  GLD16(gA1, ldsp + 8192 + w * 1024);
  GLD16(gB0, ldsp + 32768 + w * 1024);
  if constexpr (BN == 256) GLD16(gB1, ldsp + 32768 + 8192 + w * 1024);

  const int NT = K >> 5;
  short8 bq[NREP], aq[4];

  for (int kt = 0; kt < NT - 1; ++kt) {
    const int b = kt & 1, nb = b ^ 1;
    const int k1 = (kt + 1) << 5;
    // stage kt+1 (full K-tile ahead of its wait)
    GLD16(gA0 + k1, ldsp + nb * 16384 + w * 1024);
    GLD16(gA1 + k1, ldsp + nb * 16384 + 8192 + w * 1024);
    GLD16(gB0 + k1, ldsp + 32768 + nb * BNB + w * 1024);
    if constexpr (BN == 256) GLD16(gB1 + k1, ldsp + 32768 + nb * BNB + 8192 + w * 1024);
    // counted drain: kt's 4(3) loads landed, kt+1's stay in flight
    if constexpr (BN == 256) asm volatile("s_waitcnt vmcnt(4)" ::: "memory");
    else                     asm volatile("s_waitcnt vmcnt(3)" ::: "memory");
    __builtin_amdgcn_s_barrier();

    const char* pa = ldsp + b * 16384 + paOff;
    const char* pb = ldsp + b * BNB + pbOff;
#pragma unroll
    for (int n = 0; n < NREP; n++) bq[n] = *(const short8*)(pb + n * 1024);
#pragma unroll
    for (int m = 0; m < 4; m++) aq[m] = *(const short8*)(pa + m * 1024);
    __builtin_amdgcn_s_setprio(1);
#pragma unroll
    for (int m = 0; m < 4; m++)
#pragma unroll
      for (int n = 0; n < NREP; n++)
        acc[m][n] = __builtin_amdgcn_mfma_f32_16x16x32_bf16(aq[m], bq[n], acc[m][n], 0, 0, 0);
    __builtin_amdgcn_s_setprio(0);
    __builtin_amdgcn_s_barrier();
#pragma unroll
    for (int m = 0; m < 4; m++) aq[m] = *(const short8*)(pa + (m + 4) * 1024);
    __builtin_amdgcn_s_setprio(1);
#pragma unroll
    for (int m = 0; m < 4; m++)
#pragma unroll
      for (int n = 0; n < NREP; n++)
        acc[m + 4][n] = __builtin_amdgcn_mfma_f32_16x16x32_bf16(aq[m], bq[n], acc[m + 4][n], 0, 0, 0);
    __builtin_amdgcn_s_setprio(0);
    __builtin_amdgcn_s_barrier();
  }

  // tail K-tile (no stages outstanding beyond it)
  {
    const int b = (NT - 1) & 1;
    asm volatile("s_waitcnt vmcnt(0)" ::: "memory");
    __builtin_amdgcn_s_barrier();
    const char* pa = ldsp + b * 16384 + paOff;
    const char* pb = ldsp + b * BNB + pbOff;
#pragma unroll
    for (int n = 0; n < NREP; n++) bq[n] = *(const short8*)(pb + n * 1024);
#pragma unroll
    for (int m = 0; m < 8; m++) {
      short8 a = *(const short8*)(pa + m * 1024);
#pragma unroll
      for (int n = 0; n < NREP; n++)
        acc[m][n] = __builtin_amdgcn_mfma_f32_16x16x32_bf16(a, bq[n], acc[m][n], 0, 0, 0);
    }
  }

  // epilogue
  const int orow = (l >> 4) << 2;
#pragma unroll
  for (int n = 0; n < NREP; n++) {
    size_t col = bcol + (size_t)wc * WN + n * 16 + lr;
    float bv = bias[col];
#pragma unroll
    for (int m = 0; m < 8; m++) {
      size_t row = brow + (size_t)wr * 128 + m * 16 + orow;
#pragma unroll
      for (int r = 0; r < 4; r++)
        Cout[(row + r) * (size_t)N + col] = acc[m][n][r] + bv;
    }
  }
}

// ---------------------------------------------------------------------------
extern "C" void kernel_launch(void* const* d_in, const int* in_sizes, int n_in,
                              void* d_out, int out_size, void* d_ws, size_t ws_size,
                              hipStream_t stream) {
  const float* x     = (const float*)d_in[0];
  const float* coef0 = (const float*)d_in[1];
  const float* sb0   = (const float*)d_in[2];
  const float* sp0   = (const float*)d_in[3];
  const float* mask0 = (const float*)d_in[4];
  const float* bias0 = (const float*)d_in[5];
  const float* coef1 = (const float*)d_in[6];
  const float* sb1   = (const float*)d_in[7];
  const float* sp1   = (const float*)d_in[8];
  const float* mask1 = (const float*)d_in[9];
  const float* bias1 = (const float*)d_in[10];
  float* out = (float*)d_out;

  const int B = 8192, D0 = 1024, D1 = 2048, D2 = 1024;
  const int K0 = 9 * D0;   // 9216
  const int K1 = 9 * D1;   // 18432

  char* ws = (char*)d_ws;
  float*          h1  = (float*)ws;                                   // 64 MiB
  __hip_bfloat16* W   = (__hip_bfloat16*)(ws + (size_t)67108864);     // 36 MiB
  __hip_bfloat16* Aug = (__hip_bfloat16*)(ws + (size_t)104857600);

  const bool fullL1 = ws_size >= (size_t)104857600 + (size_t)B * K1 * 2;

  // ---- layer 0: full batch ----
  {
    long nw = (long)D1 * D0;
    prep_w<<<(unsigned)((nw + 255) / 256), 256, 0, stream>>>(coef0, sb0, sp0, mask0, W, D1, D0);
    long np = (long)B * (D0 / 2);
    expand_aug<<<(unsigned)((np + 255) / 256), 256, 0, stream>>>(x, Aug, np, D0);
    dim3 g0(D1 / 256, B / 256);  // (8, 32) = 256 blocks
    gemm8p<256><<<g0, 512, 0, stream>>>(Aug, W, bias0, h1, D1, K0);
  }

  // ---- layer 1 ----
  {
    long nw = (long)D2 * D1;
    prep_w<<<(unsigned)((nw + 255) / 256), 256, 0, stream>>>(coef1, sb1, sp1, mask1, W, D2, D1);
    const int CH = fullL1 ? B : 4096;
    for (int ch = 0; ch < B / CH; ch++) {
      long np = (long)CH * (D1 / 2);
      expand_aug<<<(unsigned)((np + 255) / 256), 256, 0, stream>>>(
          h1 + (size_t)ch * CH * D1, Aug, np, D1);
      dim3 g1(D2 / 128, CH / 256);  // full: (8, 32) = 256 blocks
      gemm8p<128><<<g1, 512, 0, stream>>>(Aug, W, bias1,
                                          out + (size_t)ch * CH * D2, D2, K1);
    }
  }
}

// Round 6
// 1054.676 us; speedup vs baseline: 1.3382x; 1.0685x over previous
//
#include <hip/hip_runtime.h>
#include <hip/hip_bf16.h>
#include <cstdint>

// ---------------------------------------------------------------------------
// KAN 2-layer forward as two bf16 MFMA GEMMs (fp32 output).
// Round-6 (vs r5 pass @1127us):
//  * FIX LDS swizzle: r5's ((row&3)<<4) left 2-way conflicts (8-lane issue
//    group covered only 4 of 8 16B-slots; SQ_LDS_BANK_CONFLICT 2.4e7).
//    Correct involution for 64B rows: ((row>>1)&3)<<4 -> slot
//    4*(row&1) | (kh ^ ((row>>1)&3)) is bijective per 8-lane group.
//    Applied on BOTH sides (pre-swizzled global source + swizzled ds_read).
//  * expand_aug vectorized 4 elems/thread: float4 load, 9x 8B bf16x4 stores
//    (was 10x 4B stores/2 elems -> G13 under-vectorization; aux was 390us
//    vs ~130us ideal).
// GEMM schedule (unchanged, proven): 256xBN, BK=32, 8 waves 2Mx4N, dbuf LDS,
// counted vmcnt (never 0 in loop), setprio around MFMA clusters, XCD swizzle.
// ws layout: h1 fp32 [0,64MiB) | W bf16 [64,100MiB) | Aug bf16 [100MiB,...)
// ---------------------------------------------------------------------------

typedef __attribute__((ext_vector_type(8))) short short8;
typedef __attribute__((ext_vector_type(4))) short short4v;
typedef __attribute__((ext_vector_type(4))) float f32x4;

#define GLD16(gp, lp)                                                          \
  __builtin_amdgcn_global_load_lds(                                           \
      (const __attribute__((address_space(1))) unsigned int*)(gp),             \
      (__attribute__((address_space(3))) unsigned int*)(lp), 16, 0, 0)

__device__ __forceinline__ unsigned short f2bf(float f) {
  __hip_bfloat16 h = __float2bfloat16(f);
  return *reinterpret_cast<unsigned short*>(&h);
}

// ---- pack weights: W[o, c*I+i], bf16 --------------------------------------
__global__ void prep_w(const float* __restrict__ coef, const float* __restrict__ sb,
                       const float* __restrict__ sp, const float* __restrict__ mask,
                       __hip_bfloat16* __restrict__ W, int O, int I) {
  long idx = (long)blockIdx.x * blockDim.x + threadIdx.x;
  long total = (long)O * I;
  if (idx >= total) return;
  int i = (int)(idx % I);
  int o = (int)(idx / I);
  float mk  = mask[idx];
  float spm = sp[idx] * mk;
  float sbm = sb[idx] * mk;
  const float4* cf = (const float4*)(coef + (size_t)idx * 8);
  float4 c0 = cf[0], c1 = cf[1];
  __hip_bfloat16* base = W + (size_t)o * (size_t)(9 * I) + i;
  base[(size_t)0 * I] = __float2bfloat16(c0.x * spm);
  base[(size_t)1 * I] = __float2bfloat16(c0.y * spm);
  base[(size_t)2 * I] = __float2bfloat16(c0.z * spm);
  base[(size_t)3 * I] = __float2bfloat16(c0.w * spm);
  base[(size_t)4 * I] = __float2bfloat16(c1.x * spm);
  base[(size_t)5 * I] = __float2bfloat16(c1.y * spm);
  base[(size_t)6 * I] = __float2bfloat16(c1.z * spm);
  base[(size_t)7 * I] = __float2bfloat16(c1.w * spm);
  base[(size_t)8 * I] = __float2bfloat16(sbm);
}

// ---- expand activations: Aug[b, c*I+i], 4 elems/thread --------------------
// Uniform knots grid[m]=(m-3)*0.4-1.0: u=(x+2.2)*2.5, j=floor(u); nonzero
// basis c=j-3..j with cardinal cubic weights; B_c=0 otherwise (covers
// out-of-domain x, matching the reference).
__device__ __forceinline__ void basis8(float x, float* w, int& j) {
  float u  = (x + 2.2f) * 2.5f;
  float fj = floorf(u);
  j = (int)fj;
  float t  = u - fj;
  float omt = 1.0f - t;
  float t2 = t * t, t3 = t2 * t;
  w[0] = omt * omt * omt * (1.0f / 6.0f);                              // d==3
  w[1] = (3.0f * t3 - 6.0f * t2 + 4.0f) * (1.0f / 6.0f);               // d==2
  w[2] = (-3.0f * t3 + 3.0f * t2 + 3.0f * t + 1.0f) * (1.0f / 6.0f);   // d==1
  w[3] = t3 * (1.0f / 6.0f);                                           // d==0
}

__global__ void expand_aug(const float* __restrict__ src,
                           __hip_bfloat16* __restrict__ aug,
                           long totalQuads, int I) {
  long idx = (long)blockIdx.x * blockDim.x + threadIdx.x;
  if (idx >= totalQuads) return;
  int  qtr = I >> 2;
  int  iq = (int)(idx % qtr);
  long b  = idx / qtr;
  int  i  = iq << 2;
  float4 xv = *(const float4*)(src + b * (size_t)I + i);

  float w[4][4], s[4];
  int   j[4];
#pragma unroll
  for (int e = 0; e < 4; e++) {
    float xe = (e == 0) ? xv.x : (e == 1) ? xv.y : (e == 2) ? xv.z : xv.w;
    s[e] = xe / (1.0f + __expf(-xe));
    basis8(xe, w[e], j[e]);
  }

  __hip_bfloat16* base = aug + b * (size_t)(9 * I) + i;
#pragma unroll
  for (int c = 0; c < 8; c++) {
    short4v pk;
#pragma unroll
    for (int e = 0; e < 4; e++) {
      int d = j[e] - c;
      float v = 0.0f;
      v = (d == 0) ? w[e][3] : v;
      v = (d == 1) ? w[e][2] : v;
      v = (d == 2) ? w[e][1] : v;
      v = (d == 3) ? w[e][0] : v;
      pk[e] = (short)f2bf(v);
    }
    *(short4v*)(base + (size_t)c * I) = pk;
  }
  short4v ps;
#pragma unroll
  for (int e = 0; e < 4; e++) ps[e] = (short)f2bf(s[e]);
  *(short4v*)(base + (size_t)8 * I) = ps;
}

// ---- 8-phase GEMM: C[m,n] = sum_k A[m,k]*Bw[n,k] + bias[n], fp32 out ------
// BM=256 x BN (256 or 128), BK=32, 8 waves = 2M x 4N, per-wave out 128 x BN/4.
// LDS rows are 64B; element (row, kbyte) stored at kbyte ^ (((row>>1)&3)<<4):
// 8-lane issue group (row&7 = j) hits slot 4*(j&1) | (kh^(j>>1)) -> bijective
// onto all 8 16B slots => conflict-free ds_read_b128.
// global_load_lds writes linearly -> global SOURCE pre-swizzled (rule 21).
// Schedule per K-tile kt (buf b=kt&1): stage kt+1 -> vmcnt(loads/tile, never
// 0 in loop) -> barrier -> ph0 {reads, MFMA x4M} -> barrier -> ph1 -> barrier.
template <int BN>
__global__ __launch_bounds__(512, 2) void gemm8p(
    const __hip_bfloat16* __restrict__ A, const __hip_bfloat16* __restrict__ Bw,
    const float* __restrict__ bias, float* __restrict__ Cout, int N, int K) {
  constexpr int WN   = BN / 4;    // per-wave cols
  constexpr int NREP = BN / 64;   // 16-col frags per wave
  constexpr int BNB  = BN * 64;   // bytes per B buffer
  __shared__ __attribute__((aligned(16))) char lds[32768 + 2 * BNB];

  const int t = threadIdx.x;
  const int w = t >> 6, l = t & 63;
  const int wr = w >> 2, wc = w & 3;
  const int lr = l & 15;
  const int kbs = ((l >> 4) * 16) ^ (((lr >> 1) & 3) << 4);  // swizzled k-byte

  // XCD-aware bijective swizzle (grid %8 == 0)
  unsigned nwg = gridDim.x * gridDim.y;
  unsigned lin = blockIdx.y * gridDim.x + blockIdx.x;
  unsigned swz = (lin & 7) * (nwg >> 3) + (lin >> 3);
  unsigned bx = swz % gridDim.x, by = swz / gridDim.x;
  size_t brow = (size_t)by * 256, bcol = (size_t)bx * BN;

  f32x4 acc[8][NREP];
#pragma unroll
  for (int m = 0; m < 8; m++)
#pragma unroll
    for (int n = 0; n < NREP; n++) acc[m][n] = (f32x4){0.f, 0.f, 0.f, 0.f};

  // staging: thread t covers LDS-linear offset t*16 of each 8KB chunk
  // (row = t>>2, k16_lds = t&3) holding global (row, k16_lds ^ ((row>>1)&3)).
  const int srow  = t >> 2;                                   // 0..127
  const int scolb = ((t & 3) * 16) ^ (((srow >> 1) & 3) << 4);  // byte col
  const __hip_bfloat16* gA0 = A + (brow + srow) * (size_t)K + (scolb >> 1);
  const __hip_bfloat16* gA1 = gA0 + (size_t)128 * K;
  const __hip_bfloat16* gB0 = Bw + (bcol + srow) * (size_t)K + (scolb >> 1);
  const __hip_bfloat16* gB1 = gB0 + (size_t)128 * K;          // BN=256 only

  char* ldsp = (char*)lds;
  const int paOff = (wr * 128 + lr) * 64 + kbs;               // + m*1024 + b*16384
  const int pbOff = 32768 + (wc * WN + lr) * 64 + kbs;        // + n*1024 + b*BNB

  // prologue: stage K-tile 0 into buf 0
  GLD16(gA0, ldsp + w * 1024);
  GLD16(gA1, ldsp + 8192 + w * 1024);
  GLD16(gB0, ldsp + 32768 + w * 1024);
  if constexpr (BN == 256) GLD16(gB1, ldsp + 32768 + 8192 + w * 1024);

  const int NT = K >> 5;
  short8 bq[NREP], aq[4];

  for (int kt = 0; kt < NT - 1; ++kt) {
    const int b = kt & 1, nb = b ^ 1;
    const int k1 = (kt + 1) << 5;
    // stage kt+1 (issued a full K-tile ahead of its wait)
    GLD16(gA0 + k1, ldsp + nb * 16384 + w * 1024);
    GLD16(gA1 + k1, ldsp + nb * 16384 + 8192 + w * 1024);
    GLD16(gB0 + k1, ldsp + 32768 + nb * BNB + w * 1024);
    if constexpr (BN == 256) GLD16(gB1 + k1, ldsp + 32768 + nb * BNB + 8192 + w * 1024);
    // counted drain: kt's loads landed, kt+1's stay in flight
    if constexpr (BN == 256) asm volatile("s_waitcnt vmcnt(4)" ::: "memory");
    else                     asm volatile("s_waitcnt vmcnt(3)" ::: "memory");
    __builtin_amdgcn_s_barrier();

    const char* pa = ldsp + b * 16384 + paOff;
    const char* pb = ldsp + b * BNB + pbOff;
#pragma unroll
    for (int n = 0; n < NREP; n++) bq[n] = *(const short8*)(pb + n * 1024);
#pragma unroll
    for (int m = 0; m < 4; m++) aq[m] = *(const short8*)(pa + m * 1024);
    __builtin_amdgcn_s_setprio(1);
#pragma unroll
    for (int m = 0; m < 4; m++)
#pragma unroll
      for (int n = 0; n < NREP; n++)
        acc[m][n] = __builtin_amdgcn_mfma_f32_16x16x32_bf16(aq[m], bq[n], acc[m][n], 0, 0, 0);
    __builtin_amdgcn_s_setprio(0);
    __builtin_amdgcn_s_barrier();
#pragma unroll
    for (int m = 0; m < 4; m++) aq[m] = *(const short8*)(pa + (m + 4) * 1024);
    __builtin_amdgcn_s_setprio(1);
#pragma unroll
    for (int m = 0; m < 4; m++)
#pragma unroll
      for (int n = 0; n < NREP; n++)
        acc[m + 4][n] = __builtin_amdgcn_mfma_f32_16x16x32_bf16(aq[m], bq[n], acc[m + 4][n], 0, 0, 0);
    __builtin_amdgcn_s_setprio(0);
    __builtin_amdgcn_s_barrier();
  }

  // tail K-tile
  {
    const int b = (NT - 1) & 1;
    asm volatile("s_waitcnt vmcnt(0)" ::: "memory");
    __builtin_amdgcn_s_barrier();
    const char* pa = ldsp + b * 16384 + paOff;
    const char* pb = ldsp + b * BNB + pbOff;
#pragma unroll
    for (int n = 0; n < NREP; n++) bq[n] = *(const short8*)(pb + n * 1024);
#pragma unroll
    for (int m = 0; m < 8; m++) {
      short8 a = *(const short8*)(pa + m * 1024);
#pragma unroll
      for (int n = 0; n < NREP; n++)
        acc[m][n] = __builtin_amdgcn_mfma_f32_16x16x32_bf16(a, bq[n], acc[m][n], 0, 0, 0);
    }
  }

  // epilogue
  const int orow = (l >> 4) << 2;
#pragma unroll
  for (int n = 0; n < NREP; n++) {
    size_t col = bcol + (size_t)wc * WN + n * 16 + lr;
    float bv = bias[col];
#pragma unroll
    for (int m = 0; m < 8; m++) {
      size_t row = brow + (size_t)wr * 128 + m * 16 + orow;
#pragma unroll
      for (int r = 0; r < 4; r++)
        Cout[(row + r) * (size_t)N + col] = acc[m][n][r] + bv;
    }
  }
}

// ---------------------------------------------------------------------------
extern "C" void kernel_launch(void* const* d_in, const int* in_sizes, int n_in,
                              void* d_out, int out_size, void* d_ws, size_t ws_size,
                              hipStream_t stream) {
  const float* x     = (const float*)d_in[0];
  const float* coef0 = (const float*)d_in[1];
  const float* sb0   = (const float*)d_in[2];
  const float* sp0   = (const float*)d_in[3];
  const float* mask0 = (const float*)d_in[4];
  const float* bias0 = (const float*)d_in[5];
  const float* coef1 = (const float*)d_in[6];
  const float* sb1   = (const float*)d_in[7];
  const float* sp1   = (const float*)d_in[8];
  const float* mask1 = (const float*)d_in[9];
  const float* bias1 = (const float*)d_in[10];
  float* out = (float*)d_out;

  const int B = 8192, D0 = 1024, D1 = 2048, D2 = 1024;
  const int K0 = 9 * D0;   // 9216
  const int K1 = 9 * D1;   // 18432

  char* ws = (char*)d_ws;
  float*          h1  = (float*)ws;                                   // 64 MiB
  __hip_bfloat16* W   = (__hip_bfloat16*)(ws + (size_t)67108864);     // 36 MiB
  __hip_bfloat16* Aug = (__hip_bfloat16*)(ws + (size_t)104857600);

  const bool fullL1 = ws_size >= (size_t)104857600 + (size_t)B * K1 * 2;

  // ---- layer 0: full batch ----
  {
    long nw = (long)D1 * D0;
    prep_w<<<(unsigned)((nw + 255) / 256), 256, 0, stream>>>(coef0, sb0, sp0, mask0, W, D1, D0);
    long np = (long)B * (D0 / 4);
    expand_aug<<<(unsigned)((np + 255) / 256), 256, 0, stream>>>(x, Aug, np, D0);
    dim3 g0(D1 / 256, B / 256);  // (8, 32) = 256 blocks
    gemm8p<256><<<g0, 512, 0, stream>>>(Aug, W, bias0, h1, D1, K0);
  }

  // ---- layer 1 ----
  {
    long nw = (long)D2 * D1;
    prep_w<<<(unsigned)((nw + 255) / 256), 256, 0, stream>>>(coef1, sb1, sp1, mask1, W, D2, D1);
    const int CH = fullL1 ? B : 4096;
    for (int ch = 0; ch < B / CH; ch++) {
      long np = (long)CH * (D1 / 4);
      expand_aug<<<(unsigned)((np + 255) / 256), 256, 0, stream>>>(
          h1 + (size_t)ch * CH * D1, Aug, np, D1);
      dim3 g1(D2 / 128, CH / 256);  // full: (8, 32) = 256 blocks
      gemm8p<128><<<g1, 512, 0, stream>>>(Aug, W, bias1,
                                          out + (size_t)ch * CH * D2, D2, K1);
    }
  }
}

// Round 7
// 986.809 us; speedup vs baseline: 1.4303x; 1.0688x over previous
//
#include <hip/hip_runtime.h>
#include <hip/hip_bf16.h>
#include <cstdint>

// ---------------------------------------------------------------------------
// KAN 2-layer forward as two bf16 MFMA GEMMs (fp32 output).
// Round-7 (vs r6 pass @1055us): GEMM prefetch depth 1 -> 2.
//   3 LDS buffers (96KB BN=256 / 72KB BN=128), stage kt+2 while computing kt,
//   steady-state s_waitcnt vmcnt(2L) (never 0 in loop). Rationale: per-K-tile
//   MFMA ~310cy < HBM/L2-miss latency 500-900cy; depth-1 left ~300-600cy
//   stall per tile (gemm at 342us vs 124us MFMA-ideal). Depth-2 doubles cover.
//   WAR safety: buffer q staged in iter kt was last read in iter kt-1, whose
//   compute block ends with s_barrier before kt's stage issues (all ds_reads
//   consumed by MFMA via lgkmcnt before that barrier).
// Unchanged from r6 (proven): bijective LDS swizzle ((row>>1)&3)<<4 both-sides
// (bank conflicts == 0), XCD swizzle, setprio, epilogue, aux kernels.
// ws layout: h1 fp32 [0,64MiB) | W bf16 [64,100MiB) | Aug bf16 [100MiB,...)
// ---------------------------------------------------------------------------

typedef __attribute__((ext_vector_type(8))) short short8;
typedef __attribute__((ext_vector_type(4))) short short4v;
typedef __attribute__((ext_vector_type(4))) float f32x4;

#define GLD16(gp, lp)                                                          \
  __builtin_amdgcn_global_load_lds(                                           \
      (const __attribute__((address_space(1))) unsigned int*)(gp),             \
      (__attribute__((address_space(3))) unsigned int*)(lp), 16, 0, 0)

__device__ __forceinline__ unsigned short f2bf(float f) {
  __hip_bfloat16 h = __float2bfloat16(f);
  return *reinterpret_cast<unsigned short*>(&h);
}

// ---- pack weights: W[o, c*I+i], bf16 --------------------------------------
__global__ void prep_w(const float* __restrict__ coef, const float* __restrict__ sb,
                       const float* __restrict__ sp, const float* __restrict__ mask,
                       __hip_bfloat16* __restrict__ W, int O, int I) {
  long idx = (long)blockIdx.x * blockDim.x + threadIdx.x;
  long total = (long)O * I;
  if (idx >= total) return;
  int i = (int)(idx % I);
  int o = (int)(idx / I);
  float mk  = mask[idx];
  float spm = sp[idx] * mk;
  float sbm = sb[idx] * mk;
  const float4* cf = (const float4*)(coef + (size_t)idx * 8);
  float4 c0 = cf[0], c1 = cf[1];
  __hip_bfloat16* base = W + (size_t)o * (size_t)(9 * I) + i;
  base[(size_t)0 * I] = __float2bfloat16(c0.x * spm);
  base[(size_t)1 * I] = __float2bfloat16(c0.y * spm);
  base[(size_t)2 * I] = __float2bfloat16(c0.z * spm);
  base[(size_t)3 * I] = __float2bfloat16(c0.w * spm);
  base[(size_t)4 * I] = __float2bfloat16(c1.x * spm);
  base[(size_t)5 * I] = __float2bfloat16(c1.y * spm);
  base[(size_t)6 * I] = __float2bfloat16(c1.z * spm);
  base[(size_t)7 * I] = __float2bfloat16(c1.w * spm);
  base[(size_t)8 * I] = __float2bfloat16(sbm);
}

// ---- expand activations: Aug[b, c*I+i], 4 elems/thread --------------------
__device__ __forceinline__ void basis8(float x, float* w, int& j) {
  float u  = (x + 2.2f) * 2.5f;
  float fj = floorf(u);
  j = (int)fj;
  float t  = u - fj;
  float omt = 1.0f - t;
  float t2 = t * t, t3 = t2 * t;
  w[0] = omt * omt * omt * (1.0f / 6.0f);                              // d==3
  w[1] = (3.0f * t3 - 6.0f * t2 + 4.0f) * (1.0f / 6.0f);               // d==2
  w[2] = (-3.0f * t3 + 3.0f * t2 + 3.0f * t + 1.0f) * (1.0f / 6.0f);   // d==1
  w[3] = t3 * (1.0f / 6.0f);                                           // d==0
}

__global__ void expand_aug(const float* __restrict__ src,
                           __hip_bfloat16* __restrict__ aug,
                           long totalQuads, int I) {
  long idx = (long)blockIdx.x * blockDim.x + threadIdx.x;
  if (idx >= totalQuads) return;
  int  qtr = I >> 2;
  int  iq = (int)(idx % qtr);
  long b  = idx / qtr;
  int  i  = iq << 2;
  float4 xv = *(const float4*)(src + b * (size_t)I + i);

  float w[4][4], s[4];
  int   j[4];
#pragma unroll
  for (int e = 0; e < 4; e++) {
    float xe = (e == 0) ? xv.x : (e == 1) ? xv.y : (e == 2) ? xv.z : xv.w;
    s[e] = xe / (1.0f + __expf(-xe));
    basis8(xe, w[e], j[e]);
  }

  __hip_bfloat16* base = aug + b * (size_t)(9 * I) + i;
#pragma unroll
  for (int c = 0; c < 8; c++) {
    short4v pk;
#pragma unroll
    for (int e = 0; e < 4; e++) {
      int d = j[e] - c;
      float v = 0.0f;
      v = (d == 0) ? w[e][3] : v;
      v = (d == 1) ? w[e][2] : v;
      v = (d == 2) ? w[e][1] : v;
      v = (d == 3) ? w[e][0] : v;
      pk[e] = (short)f2bf(v);
    }
    *(short4v*)(base + (size_t)c * I) = pk;
  }
  short4v ps;
#pragma unroll
  for (int e = 0; e < 4; e++) ps[e] = (short)f2bf(s[e]);
  *(short4v*)(base + (size_t)8 * I) = ps;
}

// ---- depth-2 pipelined GEMM: C = A * Bw^T + bias, fp32 out ----------------
// BM=256 x BN (256/128), BK=32, 8 waves 2Mx4N, 3 LDS buffers.
// LDS rows 64B; element (row,kbyte) at kbyte ^ (((row>>1)&3)<<4) (bijective
// per 8-lane group -> 0 bank conflicts, verified r6). Pre-swizzled global
// source + swizzled ds_read (rule 21 both-sides).
template <int BN>
__global__ __launch_bounds__(512, 2) void gemm8p(
    const __hip_bfloat16* __restrict__ A, const __hip_bfloat16* __restrict__ Bw,
    const float* __restrict__ bias, float* __restrict__ Cout, int N, int K) {
  constexpr int WN   = BN / 4;        // per-wave cols
  constexpr int NREP = BN / 64;       // 16-col frags per wave
  constexpr int BNB  = BN * 64;       // B bytes per buffer
  constexpr int BUFB = 16384 + BNB;   // bytes per buffer (A + B)
  __shared__ __attribute__((aligned(16))) char lds[3 * BUFB];

  const int t = threadIdx.x;
  const int w = t >> 6, l = t & 63;
  const int wr = w >> 2, wc = w & 3;
  const int lr = l & 15;
  const int kbs = ((l >> 4) * 16) ^ (((lr >> 1) & 3) << 4);  // swizzled k-byte

  // XCD-aware bijective swizzle (grid %8 == 0)
  unsigned nwg = gridDim.x * gridDim.y;
  unsigned lin = blockIdx.y * gridDim.x + blockIdx.x;
  unsigned swz = (lin & 7) * (nwg >> 3) + (lin >> 3);
  unsigned bx = swz % gridDim.x, by = swz / gridDim.x;
  size_t brow = (size_t)by * 256, bcol = (size_t)bx * BN;

  f32x4 acc[8][NREP];
#pragma unroll
  for (int m = 0; m < 8; m++)
#pragma unroll
    for (int n = 0; n < NREP; n++) acc[m][n] = (f32x4){0.f, 0.f, 0.f, 0.f};

  // staging: thread t covers LDS-linear offset t*16 of each 8KB chunk
  const int srow  = t >> 2;                                     // 0..127
  const int scolb = ((t & 3) * 16) ^ (((srow >> 1) & 3) << 4);  // byte col
  const __hip_bfloat16* gA0 = A + (brow + srow) * (size_t)K + (scolb >> 1);
  const __hip_bfloat16* gA1 = gA0 + (size_t)128 * K;
  const __hip_bfloat16* gB0 = Bw + (bcol + srow) * (size_t)K + (scolb >> 1);
  const __hip_bfloat16* gB1 = gB0 + (size_t)128 * K;            // BN=256 only

  char* ldsp = (char*)lds;
  const int paOff = (wr * 128 + lr) * 64 + kbs;            // + m*1024 + q*BUFB
  const int pbOff = 16384 + (wc * WN + lr) * 64 + kbs;     // + n*1024 + q*BUFB

  auto STAGE = [&](int kt, int q) {
    const int k = kt << 5;
    char* bp = ldsp + q * BUFB;
    GLD16(gA0 + k, bp + w * 1024);
    GLD16(gA1 + k, bp + 8192 + w * 1024);
    GLD16(gB0 + k, bp + 16384 + w * 1024);
    if constexpr (BN == 256) GLD16(gB1 + k, bp + 16384 + 8192 + w * 1024);
  };

  short8 bq[NREP], aq[4];
  auto COMPUTE = [&](int q) {
    const char* pa = ldsp + q * BUFB + paOff;
    const char* pb = ldsp + q * BUFB + pbOff;
#pragma unroll
    for (int n = 0; n < NREP; n++) bq[n] = *(const short8*)(pb + n * 1024);
#pragma unroll
    for (int m = 0; m < 4; m++) aq[m] = *(const short8*)(pa + m * 1024);
    __builtin_amdgcn_s_setprio(1);
#pragma unroll
    for (int m = 0; m < 4; m++)
#pragma unroll
      for (int n = 0; n < NREP; n++)
        acc[m][n] = __builtin_amdgcn_mfma_f32_16x16x32_bf16(aq[m], bq[n], acc[m][n], 0, 0, 0);
    __builtin_amdgcn_s_setprio(0);
    __builtin_amdgcn_s_barrier();
#pragma unroll
    for (int m = 0; m < 4; m++) aq[m] = *(const short8*)(pa + (m + 4) * 1024);
    __builtin_amdgcn_s_setprio(1);
#pragma unroll
    for (int m = 0; m < 4; m++)
#pragma unroll
      for (int n = 0; n < NREP; n++)
        acc[m + 4][n] = __builtin_amdgcn_mfma_f32_16x16x32_bf16(aq[m], bq[n], acc[m + 4][n], 0, 0, 0);
    __builtin_amdgcn_s_setprio(0);
    __builtin_amdgcn_s_barrier();
  };

  const int NT = K >> 5;  // >= 3 always here (288 / 576)

  // prologue: tiles 0,1 into buffers 0,1
  STAGE(0, 0);
  STAGE(1, 1);

  int q0 = 0;  // buffer holding tile kt
  for (int kt = 0; kt < NT - 2; ++kt) {
    int q2 = q0 + 2; if (q2 >= 3) q2 -= 3;
    STAGE(kt + 2, q2);
    // keep 2 tiles (2L loads) in flight; tile kt's loads are drained
    if constexpr (BN == 256) asm volatile("s_waitcnt vmcnt(8)" ::: "memory");
    else                     asm volatile("s_waitcnt vmcnt(6)" ::: "memory");
    __builtin_amdgcn_s_barrier();
    COMPUTE(q0);
    q0 = (q0 == 2) ? 0 : q0 + 1;
  }
  // tail tile NT-2: only NT-1's loads may remain in flight
  if constexpr (BN == 256) asm volatile("s_waitcnt vmcnt(4)" ::: "memory");
  else                     asm volatile("s_waitcnt vmcnt(3)" ::: "memory");
  __builtin_amdgcn_s_barrier();
  COMPUTE(q0);
  q0 = (q0 == 2) ? 0 : q0 + 1;
  // tail tile NT-1
  asm volatile("s_waitcnt vmcnt(0)" ::: "memory");
  __builtin_amdgcn_s_barrier();
  COMPUTE(q0);

  // epilogue
  const int orow = (l >> 4) << 2;
#pragma unroll
  for (int n = 0; n < NREP; n++) {
    size_t col = bcol + (size_t)wc * WN + n * 16 + lr;
    float bv = bias[col];
#pragma unroll
    for (int m = 0; m < 8; m++) {
      size_t row = brow + (size_t)wr * 128 + m * 16 + orow;
#pragma unroll
      for (int r = 0; r < 4; r++)
        Cout[(row + r) * (size_t)N + col] = acc[m][n][r] + bv;
    }
  }
}

// ---------------------------------------------------------------------------
extern "C" void kernel_launch(void* const* d_in, const int* in_sizes, int n_in,
                              void* d_out, int out_size, void* d_ws, size_t ws_size,
                              hipStream_t stream) {
  const float* x     = (const float*)d_in[0];
  const float* coef0 = (const float*)d_in[1];
  const float* sb0   = (const float*)d_in[2];
  const float* sp0   = (const float*)d_in[3];
  const float* mask0 = (const float*)d_in[4];
  const float* bias0 = (const float*)d_in[5];
  const float* coef1 = (const float*)d_in[6];
  const float* sb1   = (const float*)d_in[7];
  const float* sp1   = (const float*)d_in[8];
  const float* mask1 = (const float*)d_in[9];
  const float* bias1 = (const float*)d_in[10];
  float* out = (float*)d_out;

  const int B = 8192, D0 = 1024, D1 = 2048, D2 = 1024;
  const int K0 = 9 * D0;   // 9216
  const int K1 = 9 * D1;   // 18432

  char* ws = (char*)d_ws;
  float*          h1  = (float*)ws;                                   // 64 MiB
  __hip_bfloat16* W   = (__hip_bfloat16*)(ws + (size_t)67108864);     // 36 MiB
  __hip_bfloat16* Aug = (__hip_bfloat16*)(ws + (size_t)104857600);

  const bool fullL1 = ws_size >= (size_t)104857600 + (size_t)B * K1 * 2;

  // ---- layer 0: full batch ----
  {
    long nw = (long)D1 * D0;
    prep_w<<<(unsigned)((nw + 255) / 256), 256, 0, stream>>>(coef0, sb0, sp0, mask0, W, D1, D0);
    long np = (long)B * (D0 / 4);
    expand_aug<<<(unsigned)((np + 255) / 256), 256, 0, stream>>>(x, Aug, np, D0);
    dim3 g0(D1 / 256, B / 256);  // (8, 32) = 256 blocks
    gemm8p<256><<<g0, 512, 0, stream>>>(Aug, W, bias0, h1, D1, K0);
  }

  // ---- layer 1 ----
  {
    long nw = (long)D2 * D1;
    prep_w<<<(unsigned)((nw + 255) / 256), 256, 0, stream>>>(coef1, sb1, sp1, mask1, W, D2, D1);
    const int CH = fullL1 ? B : 4096;
    for (int ch = 0; ch < B / CH; ch++) {
      long np = (long)CH * (D1 / 4);
      expand_aug<<<(unsigned)((np + 255) / 256), 256, 0, stream>>>(
          h1 + (size_t)ch * CH * D1, Aug, np, D1);
      dim3 g1(D2 / 128, CH / 256);  // full: (8, 32) = 256 blocks
      gemm8p<128><<<g1, 512, 0, stream>>>(Aug, W, bias1,
                                          out + (size_t)ch * CH * D2, D2, K1);
    }
  }
}

// Round 8
// 984.133 us; speedup vs baseline: 1.4341x; 1.0027x over previous
//
#include <hip/hip_runtime.h>
#include <hip/hip_bf16.h>
#include <cstdint>

// ---------------------------------------------------------------------------
// KAN 2-layer forward as two bf16 MFMA GEMMs (fp32 output).
// Round-8 (vs r7 pass @987us):
//  1) GEMM: removed the mid-tile barrier inside COMPUTE. With 3 buffers the
//     stage (q2) never conflicts with reads (q0); the barrier only blocked
//     the compiler from interleaving phase-1 ds_reads under phase-0 MFMAs.
//     Required barriers kept: post-vmcnt (cross-wave LDS visibility) and
//     end-of-compute (stops a wave racing into re-staging a buffer others
//     still read).
//  2) K-order permuted to i-block-major: k = (i/32)*288 + c*32 + (i%32)
//     in expand_aug + prep_w (GEMM agnostic: A and W permuted identically).
//     All 9 channel stores per element now span 576B (was 18KB) -> tests
//     the store-locality theory for the stagnant ~360us aux residual.
// Proven, unchanged: bijective LDS swizzle (0 conflicts), XCD swizzle,
// depth-2 prefetch w/ counted vmcnt, setprio, fragment/epilogue math.
// ws layout: h1 fp32 [0,64MiB) | W bf16 [64,100MiB) | Aug bf16 [100MiB,...)
// ---------------------------------------------------------------------------

typedef __attribute__((ext_vector_type(8))) short short8;
typedef __attribute__((ext_vector_type(4))) short short4v;
typedef __attribute__((ext_vector_type(4))) float f32x4;

#define GLD16(gp, lp)                                                          \
  __builtin_amdgcn_global_load_lds(                                           \
      (const __attribute__((address_space(1))) unsigned int*)(gp),             \
      (__attribute__((address_space(3))) unsigned int*)(lp), 16, 0, 0)

__device__ __forceinline__ unsigned short f2bf(float f) {
  __hip_bfloat16 h = __float2bfloat16(f);
  return *reinterpret_cast<unsigned short*>(&h);
}

// ---- pack weights: W[o, kperm(c,i)], bf16 ---------------------------------
// kperm(c,i) = (i/32)*288 + c*32 + (i%32)
__global__ void prep_w(const float* __restrict__ coef, const float* __restrict__ sb,
                       const float* __restrict__ sp, const float* __restrict__ mask,
                       __hip_bfloat16* __restrict__ W, int O, int I) {
  long idx = (long)blockIdx.x * blockDim.x + threadIdx.x;
  long total = (long)O * I;
  if (idx >= total) return;
  int i = (int)(idx % I);
  int o = (int)(idx / I);
  float mk  = mask[idx];
  float spm = sp[idx] * mk;
  float sbm = sb[idx] * mk;
  const float4* cf = (const float4*)(coef + (size_t)idx * 8);
  float4 c0 = cf[0], c1 = cf[1];
  __hip_bfloat16* base = W + (size_t)o * (size_t)(9 * I) + (i >> 5) * 288 + (i & 31);
  base[0 * 32] = __float2bfloat16(c0.x * spm);
  base[1 * 32] = __float2bfloat16(c0.y * spm);
  base[2 * 32] = __float2bfloat16(c0.z * spm);
  base[3 * 32] = __float2bfloat16(c0.w * spm);
  base[4 * 32] = __float2bfloat16(c1.x * spm);
  base[5 * 32] = __float2bfloat16(c1.y * spm);
  base[6 * 32] = __float2bfloat16(c1.z * spm);
  base[7 * 32] = __float2bfloat16(c1.w * spm);
  base[8 * 32] = __float2bfloat16(sbm);
}

// ---- expand activations: Aug[b, kperm(c,i)], 4 elems/thread ---------------
__device__ __forceinline__ void basis8(float x, float* w, int& j) {
  float u  = (x + 2.2f) * 2.5f;
  float fj = floorf(u);
  j = (int)fj;
  float t  = u - fj;
  float omt = 1.0f - t;
  float t2 = t * t, t3 = t2 * t;
  w[0] = omt * omt * omt * (1.0f / 6.0f);                              // d==3
  w[1] = (3.0f * t3 - 6.0f * t2 + 4.0f) * (1.0f / 6.0f);               // d==2
  w[2] = (-3.0f * t3 + 3.0f * t2 + 3.0f * t + 1.0f) * (1.0f / 6.0f);   // d==1
  w[3] = t3 * (1.0f / 6.0f);                                           // d==0
}

__global__ void expand_aug(const float* __restrict__ src,
                           __hip_bfloat16* __restrict__ aug,
                           long totalQuads, int I) {
  long idx = (long)blockIdx.x * blockDim.x + threadIdx.x;
  if (idx >= totalQuads) return;
  int  qtr = I >> 2;
  int  iq = (int)(idx % qtr);
  long b  = idx / qtr;
  int  i  = iq << 2;            // quad stays within one 32-block (32 | I)
  float4 xv = *(const float4*)(src + b * (size_t)I + i);

  float w[4][4], s[4];
  int   j[4];
#pragma unroll
  for (int e = 0; e < 4; e++) {
    float xe = (e == 0) ? xv.x : (e == 1) ? xv.y : (e == 2) ? xv.z : xv.w;
    s[e] = xe / (1.0f + __expf(-xe));
    basis8(xe, w[e], j[e]);
  }

  __hip_bfloat16* base = aug + b * (size_t)(9 * I) + (i >> 5) * 288 + (i & 31);
#pragma unroll
  for (int c = 0; c < 8; c++) {
    short4v pk;
#pragma unroll
    for (int e = 0; e < 4; e++) {
      int d = j[e] - c;
      float v = 0.0f;
      v = (d == 0) ? w[e][3] : v;
      v = (d == 1) ? w[e][2] : v;
      v = (d == 2) ? w[e][1] : v;
      v = (d == 3) ? w[e][0] : v;
      pk[e] = (short)f2bf(v);
    }
    *(short4v*)(base + c * 32) = pk;
  }
  short4v ps;
#pragma unroll
  for (int e = 0; e < 4; e++) ps[e] = (short)f2bf(s[e]);
  *(short4v*)(base + 8 * 32) = ps;
}

// ---- depth-2 pipelined GEMM: C = A * Bw^T + bias, fp32 out ----------------
// BM=256 x BN (256/128), BK=32, 8 waves 2Mx4N, 3 LDS buffers.
// LDS rows 64B; element (row,kbyte) at kbyte ^ (((row>>1)&3)<<4) (bijective
// per 8-lane group -> 0 bank conflicts, verified r6). Pre-swizzled global
// source + swizzled ds_read (rule 21 both-sides).
template <int BN>
__global__ __launch_bounds__(512, 2) void gemm8p(
    const __hip_bfloat16* __restrict__ A, const __hip_bfloat16* __restrict__ Bw,
    const float* __restrict__ bias, float* __restrict__ Cout, int N, int K) {
  constexpr int WN   = BN / 4;        // per-wave cols
  constexpr int NREP = BN / 64;       // 16-col frags per wave
  constexpr int BNB  = BN * 64;       // B bytes per buffer
  constexpr int BUFB = 16384 + BNB;   // bytes per buffer (A + B)
  __shared__ __attribute__((aligned(16))) char lds[3 * BUFB];

  const int t = threadIdx.x;
  const int w = t >> 6, l = t & 63;
  const int wr = w >> 2, wc = w & 3;
  const int lr = l & 15;
  const int kbs = ((l >> 4) * 16) ^ (((lr >> 1) & 3) << 4);  // swizzled k-byte

  // XCD-aware bijective swizzle (grid %8 == 0)
  unsigned nwg = gridDim.x * gridDim.y;
  unsigned lin = blockIdx.y * gridDim.x + blockIdx.x;
  unsigned swz = (lin & 7) * (nwg >> 3) + (lin >> 3);
  unsigned bx = swz % gridDim.x, by = swz / gridDim.x;
  size_t brow = (size_t)by * 256, bcol = (size_t)bx * BN;

  f32x4 acc[8][NREP];
#pragma unroll
  for (int m = 0; m < 8; m++)
#pragma unroll
    for (int n = 0; n < NREP; n++) acc[m][n] = (f32x4){0.f, 0.f, 0.f, 0.f};

  // staging: thread t covers LDS-linear offset t*16 of each 8KB chunk
  const int srow  = t >> 2;                                     // 0..127
  const int scolb = ((t & 3) * 16) ^ (((srow >> 1) & 3) << 4);  // byte col
  const __hip_bfloat16* gA0 = A + (brow + srow) * (size_t)K + (scolb >> 1);
  const __hip_bfloat16* gA1 = gA0 + (size_t)128 * K;
  const __hip_bfloat16* gB0 = Bw + (bcol + srow) * (size_t)K + (scolb >> 1);
  const __hip_bfloat16* gB1 = gB0 + (size_t)128 * K;            // BN=256 only

  char* ldsp = (char*)lds;
  const int paOff = (wr * 128 + lr) * 64 + kbs;            // + m*1024 + q*BUFB
  const int pbOff = 16384 + (wc * WN + lr) * 64 + kbs;     // + n*1024 + q*BUFB

  auto STAGE = [&](int kt, int q) {
    const int k = kt << 5;
    char* bp = ldsp + q * BUFB;
    GLD16(gA0 + k, bp + w * 1024);
    GLD16(gA1 + k, bp + 8192 + w * 1024);
    GLD16(gB0 + k, bp + 16384 + w * 1024);
    if constexpr (BN == 256) GLD16(gB1 + k, bp + 16384 + 8192 + w * 1024);
  };

  short8 bq[NREP], aq[4];
  auto COMPUTE = [&](int q) {
    const char* pa = ldsp + q * BUFB + paOff;
    const char* pb = ldsp + q * BUFB + pbOff;
#pragma unroll
    for (int n = 0; n < NREP; n++) bq[n] = *(const short8*)(pb + n * 1024);
#pragma unroll
    for (int m = 0; m < 4; m++) aq[m] = *(const short8*)(pa + m * 1024);
    __builtin_amdgcn_s_setprio(1);
#pragma unroll
    for (int m = 0; m < 4; m++)
#pragma unroll
      for (int n = 0; n < NREP; n++)
        acc[m][n] = __builtin_amdgcn_mfma_f32_16x16x32_bf16(aq[m], bq[n], acc[m][n], 0, 0, 0);
    __builtin_amdgcn_s_setprio(0);
    // no mid-tile barrier: stage targets q2 != q0; letting the compiler
    // interleave the next reads under the MFMA cluster is the point.
#pragma unroll
    for (int m = 0; m < 4; m++) aq[m] = *(const short8*)(pa + (m + 4) * 1024);
    __builtin_amdgcn_s_setprio(1);
#pragma unroll
    for (int m = 0; m < 4; m++)
#pragma unroll
      for (int n = 0; n < NREP; n++)
        acc[m + 4][n] = __builtin_amdgcn_mfma_f32_16x16x32_bf16(aq[m], bq[n], acc[m + 4][n], 0, 0, 0);
    __builtin_amdgcn_s_setprio(0);
    __builtin_amdgcn_s_barrier();   // WAR: next iter re-stages a buffer
  };

  const int NT = K >> 5;  // >= 3 always here (288 / 576)

  // prologue: tiles 0,1 into buffers 0,1
  STAGE(0, 0);
  STAGE(1, 1);

  int q0 = 0;  // buffer holding tile kt
  for (int kt = 0; kt < NT - 2; ++kt) {
    int q2 = q0 + 2; if (q2 >= 3) q2 -= 3;
    STAGE(kt + 2, q2);
    // keep 2 tiles (2L loads) in flight; tile kt's loads are drained
    if constexpr (BN == 256) asm volatile("s_waitcnt vmcnt(8)" ::: "memory");
    else                     asm volatile("s_waitcnt vmcnt(6)" ::: "memory");
    __builtin_amdgcn_s_barrier();
    COMPUTE(q0);
    q0 = (q0 == 2) ? 0 : q0 + 1;
  }
  // tail tile NT-2: only NT-1's loads may remain in flight
  if constexpr (BN == 256) asm volatile("s_waitcnt vmcnt(4)" ::: "memory");
  else                     asm volatile("s_waitcnt vmcnt(3)" ::: "memory");
  __builtin_amdgcn_s_barrier();
  COMPUTE(q0);
  q0 = (q0 == 2) ? 0 : q0 + 1;
  // tail tile NT-1
  asm volatile("s_waitcnt vmcnt(0)" ::: "memory");
  __builtin_amdgcn_s_barrier();
  COMPUTE(q0);

  // epilogue
  const int orow = (l >> 4) << 2;
#pragma unroll
  for (int n = 0; n < NREP; n++) {
    size_t col = bcol + (size_t)wc * WN + n * 16 + lr;
    float bv = bias[col];
#pragma unroll
    for (int m = 0; m < 8; m++) {
      size_t row = brow + (size_t)wr * 128 + m * 16 + orow;
#pragma unroll
      for (int r = 0; r < 4; r++)
        Cout[(row + r) * (size_t)N + col] = acc[m][n][r] + bv;
    }
  }
}

// ---------------------------------------------------------------------------
extern "C" void kernel_launch(void* const* d_in, const int* in_sizes, int n_in,
                              void* d_out, int out_size, void* d_ws, size_t ws_size,
                              hipStream_t stream) {
  const float* x     = (const float*)d_in[0];
  const float* coef0 = (const float*)d_in[1];
  const float* sb0   = (const float*)d_in[2];
  const float* sp0   = (const float*)d_in[3];
  const float* mask0 = (const float*)d_in[4];
  const float* bias0 = (const float*)d_in[5];
  const float* coef1 = (const float*)d_in[6];
  const float* sb1   = (const float*)d_in[7];
  const float* sp1   = (const float*)d_in[8];
  const float* mask1 = (const float*)d_in[9];
  const float* bias1 = (const float*)d_in[10];
  float* out = (float*)d_out;

  const int B = 8192, D0 = 1024, D1 = 2048, D2 = 1024;
  const int K0 = 9 * D0;   // 9216
  const int K1 = 9 * D1;   // 18432

  char* ws = (char*)d_ws;
  float*          h1  = (float*)ws;                                   // 64 MiB
  __hip_bfloat16* W   = (__hip_bfloat16*)(ws + (size_t)67108864);     // 36 MiB
  __hip_bfloat16* Aug = (__hip_bfloat16*)(ws + (size_t)104857600);

  const bool fullL1 = ws_size >= (size_t)104857600 + (size_t)B * K1 * 2;

  // ---- layer 0: full batch ----
  {
    long nw = (long)D1 * D0;
    prep_w<<<(unsigned)((nw + 255) / 256), 256, 0, stream>>>(coef0, sb0, sp0, mask0, W, D1, D0);
    long np = (long)B * (D0 / 4);
    expand_aug<<<(unsigned)((np + 255) / 256), 256, 0, stream>>>(x, Aug, np, D0);
    dim3 g0(D1 / 256, B / 256);  // (8, 32) = 256 blocks
    gemm8p<256><<<g0, 512, 0, stream>>>(Aug, W, bias0, h1, D1, K0);
  }

  // ---- layer 1 ----
  {
    long nw = (long)D2 * D1;
    prep_w<<<(unsigned)((nw + 255) / 256), 256, 0, stream>>>(coef1, sb1, sp1, mask1, W, D2, D1);
    const int CH = fullL1 ? B : 4096;
    for (int ch = 0; ch < B / CH; ch++) {
      long np = (long)CH * (D1 / 4);
      expand_aug<<<(unsigned)((np + 255) / 256), 256, 0, stream>>>(
          h1 + (size_t)ch * CH * D1, Aug, np, D1);
      dim3 g1(D2 / 128, CH / 256);  // full: (8, 32) = 256 blocks
      gemm8p<128><<<g1, 512, 0, stream>>>(Aug, W, bias1,
                                          out + (size_t)ch * CH * D2, D2, K1);
    }
  }
}